// Round 1
// baseline (476.477 us; speedup 1.0000x reference)
//
#include <hip/hip_runtime.h>
#include <math.h>

// Problem constants
#define B_  4
#define S_  2048
#define D_  1024
#define H_  16
#define DK_ 64
#define M_  (B_*S_)   // 8192

typedef __bf16 bf16x8 __attribute__((ext_vector_type(8)));
typedef float  f32x4  __attribute__((ext_vector_type(4)));

__device__ __forceinline__ unsigned short f2bf(float f) {
  unsigned int u = __builtin_bit_cast(unsigned int, f);
  u += 0x7fffu + ((u >> 16) & 1u);   // round to nearest even
  return (unsigned short)(u >> 16);
}

__device__ __forceinline__ f32x4 mfma16(bf16x8 a, bf16x8 b, f32x4 c) {
  return __builtin_amdgcn_mfma_f32_16x16x32_bf16(a, b, c, 0, 0, 0);
}

__device__ __forceinline__ void gl_lds16(const unsigned short* g, unsigned short* l) {
  __builtin_amdgcn_global_load_lds(
      (const __attribute__((address_space(1))) void*)g,
      (__attribute__((address_space(3))) void*)l, 16, 0, 0);
}

// ---------------------------------------------------------------- cast f32->bf16
__global__ void SAA_cast_bf16(const float* __restrict__ src,
                              unsigned short* __restrict__ dst, int n4) {
  int i = blockIdx.x * blockDim.x + threadIdx.x;
  int stride = gridDim.x * blockDim.x;
  for (; i < n4; i += stride) {
    float4 v = reinterpret_cast<const float4*>(src)[i];
    ushort4 o;
    o.x = f2bf(v.x); o.y = f2bf(v.y); o.z = f2bf(v.z); o.w = f2bf(v.w);
    reinterpret_cast<ushort4*>(dst)[i] = o;
  }
}

// ---------------------------------------------------------------- QKV GEMM
// C[m,n] = sum_k Xb[m,k] * W[n,k] + bias[n]   (torch Linear: x @ W.T + b)
// 128x128 tile, BK=32, 4 waves (2x2), each wave 64x64 (4x4 frags of 16x16).
__global__ __launch_bounds__(256)
void SAA_gemm_qkv(const unsigned short* __restrict__ Xb,
                  const unsigned short* __restrict__ Wqb,
                  const unsigned short* __restrict__ Wkb,
                  const unsigned short* __restrict__ Wvb,
                  const float* __restrict__ bq,
                  const float* __restrict__ bk,
                  const float* __restrict__ bv,
                  unsigned short* __restrict__ Qo,
                  unsigned short* __restrict__ Ko,
                  unsigned short* __restrict__ Vto)
{
  const int K = D_;
  const int wid = blockIdx.z;
  const unsigned short* W = (wid == 0) ? Wqb : ((wid == 1) ? Wkb : Wvb);
  const float* bias = (wid == 0) ? bq : ((wid == 1) ? bk : bv);

  __shared__ __attribute__((aligned(16))) unsigned short lA[128 * 32];
  __shared__ __attribute__((aligned(16))) unsigned short lB[128 * 32];

  const int t = threadIdx.x;
  const int w = t >> 6, l = t & 63;
  const int wr = w >> 1, wc = w & 1;
  const int lr = l & 15, lg = l >> 4;

  const int m0 = blockIdx.y * 128;
  const int n0 = blockIdx.x * 128;

  const unsigned short* gA = Xb + (size_t)m0 * K;
  const unsigned short* gB = W + (size_t)n0 * K;

  const int srow = t >> 2, skoff = (t & 3) * 8;

  f32x4 acc[4][4] = {};

  for (int k0 = 0; k0 < K; k0 += 32) {
    gl_lds16(gA + (size_t)srow * K + k0 + skoff,        &lA[t * 8]);
    gl_lds16(gA + (size_t)(srow + 64) * K + k0 + skoff, &lA[2048 + t * 8]);
    gl_lds16(gB + (size_t)srow * K + k0 + skoff,        &lB[t * 8]);
    gl_lds16(gB + (size_t)(srow + 64) * K + k0 + skoff, &lB[2048 + t * 8]);
    __syncthreads();

    bf16x8 af[4], bfr[4];
#pragma unroll
    for (int i = 0; i < 4; i++)
      af[i] = *reinterpret_cast<const bf16x8*>(&lA[(wr * 64 + i * 16 + lr) * 32 + lg * 8]);
#pragma unroll
    for (int j = 0; j < 4; j++)
      bfr[j] = *reinterpret_cast<const bf16x8*>(&lB[(wc * 64 + j * 16 + lr) * 32 + lg * 8]);
#pragma unroll
    for (int i = 0; i < 4; i++)
#pragma unroll
      for (int j = 0; j < 4; j++)
        acc[i][j] = mfma16(af[i], bfr[j], acc[i][j]);
    __syncthreads();
  }

  // epilogue: bias add, cast, scatter into attention layouts
#pragma unroll
  for (int j = 0; j < 4; j++) {
    const int col = n0 + wc * 64 + j * 16 + lr;   // 0..1023 = feature d
    const float bsv = bias[col];
    const int h = col >> 6, dk = col & 63;
#pragma unroll
    for (int i = 0; i < 4; i++) {
#pragma unroll
      for (int r = 0; r < 4; r++) {
        const int row = m0 + wr * 64 + i * 16 + lg * 4 + r;  // 0..8191 = token
        const int b = row >> 11, s = row & 2047;
        const unsigned short val = f2bf(acc[i][j][r] + bsv);
        if (wid == 2)
          Vto[(((size_t)b * H_ + h) * DK_ + dk) * S_ + s] = val;       // [B,H,DK,S]
        else if (wid == 0)
          Qo[(((size_t)b * H_ + h) * S_ + s) * DK_ + dk] = val;        // [B,H,S,DK]
        else
          Ko[(((size_t)b * H_ + h) * S_ + s) * DK_ + dk] = val;
      }
    }
  }
}

// ---------------------------------------------------------------- flash attention
// block = (qblock of 128, h, b); 4 waves x 32 queries; key tiles of 32.
__global__ __launch_bounds__(256)
void SAA_attn(const unsigned short* __restrict__ Q,
              const unsigned short* __restrict__ Kb,
              const unsigned short* __restrict__ Vt,
              const float* __restrict__ rw,
              const int* __restrict__ maskp,
              unsigned short* __restrict__ Cb)
{
  const int qb = blockIdx.x, h = blockIdx.y, b = blockIdx.z;
  const int q0 = qb * 128;
  const int t = threadIdx.x, w = t >> 6, l = t & 63;
  const int lr = l & 15, lg = l >> 4;
  const int mask = maskp[0];

  __shared__ __attribute__((aligned(16))) unsigned short Kt[32 * 64];   // [key][dk]
  __shared__ __attribute__((aligned(16))) unsigned short Vl[64 * 32];   // [dk][key]
  __shared__ __attribute__((aligned(16))) unsigned short Pl[4][32 * 32];

  const size_t bh = (size_t)b * H_ + h;
  const unsigned short* Qbh = Q + bh * S_ * DK_;
  const unsigned short* Kbh = Kb + bh * S_ * DK_;
  const unsigned short* Vbh = Vt + bh * DK_ * S_;
  const float* rwb = rw + b * S_;

  // Q fragments in registers: rows q0+w*32+m*16+lr, k = ks*32 + lg*8
  bf16x8 qf[2][2];
#pragma unroll
  for (int m = 0; m < 2; m++)
#pragma unroll
    for (int ks = 0; ks < 2; ks++)
      qf[m][ks] = *reinterpret_cast<const bf16x8*>(
          &Qbh[(size_t)(q0 + w * 32 + m * 16 + lr) * DK_ + ks * 32 + lg * 8]);

  f32x4 acc[2][4] = {};
  float mrun[2][4], lrun[2][4];
#pragma unroll
  for (int m = 0; m < 2; m++)
#pragma unroll
    for (int r = 0; r < 4; r++) { mrun[m][r] = -INFINITY; lrun[m][r] = 0.f; }

  const int nkt = mask ? (q0 / 32 + 4) : (S_ / 32);
  const int wqmax = q0 + w * 32 + 31;

  for (int kt = 0; kt < nkt; ++kt) {
    const int k0 = kt * 32;
    // stage K tile [32][64] and V^T tile [64][32]
    gl_lds16(Kbh + (size_t)(k0 + (t >> 3)) * DK_ + (t & 7) * 8, &Kt[t * 8]);
    gl_lds16(Vbh + (size_t)(t >> 2) * S_ + k0 + (t & 3) * 8,    &Vl[t * 8]);
    __syncthreads();

    const bool active = (!mask) || (k0 <= wqmax);
    if (active) {
      f32x4 sc[2][2] = {};
#pragma unroll
      for (int ks = 0; ks < 2; ks++) {
        bf16x8 kf0 = *reinterpret_cast<const bf16x8*>(&Kt[(lr) * 64 + ks * 32 + lg * 8]);
        bf16x8 kf1 = *reinterpret_cast<const bf16x8*>(&Kt[(16 + lr) * 64 + ks * 32 + lg * 8]);
#pragma unroll
        for (int m = 0; m < 2; m++) {
          sc[m][0] = mfma16(qf[m][ks], kf0, sc[m][0]);
          sc[m][1] = mfma16(qf[m][ks], kf1, sc[m][1]);
        }
      }
      const float rwv0 = rwb[k0 + lr];
      const float rwv1 = rwb[k0 + 16 + lr];
      const int key0 = k0 + lr, key1 = k0 + 16 + lr;
#pragma unroll
      for (int m = 0; m < 2; m++) {
#pragma unroll
        for (int r = 0; r < 4; r++) {
          const int row = q0 + w * 32 + m * 16 + lg * 4 + r;
          float v0 = sc[m][0][r], v1 = sc[m][1][r];
          if (mask && key0 > row) v0 -= 1e9f;
          if (mask && key1 > row) v1 -= 1e9f;
          v0 *= 0.125f * rwv0;
          v1 *= 0.125f * rwv1;
          float mx = fmaxf(v0, v1);
          mx = fmaxf(mx, __shfl_xor(mx, 1));
          mx = fmaxf(mx, __shfl_xor(mx, 2));
          mx = fmaxf(mx, __shfl_xor(mx, 4));
          mx = fmaxf(mx, __shfl_xor(mx, 8));
          const float mnew = fmaxf(mrun[m][r], mx);
          const float c = __expf(mrun[m][r] - mnew);
          mrun[m][r] = mnew;
          const float p0 = __expf(v0 - mnew);
          const float p1 = __expf(v1 - mnew);
          float rs = p0 + p1;
          rs += __shfl_xor(rs, 1);
          rs += __shfl_xor(rs, 2);
          rs += __shfl_xor(rs, 4);
          rs += __shfl_xor(rs, 8);
          lrun[m][r] = lrun[m][r] * c + rs;
#pragma unroll
          for (int dt = 0; dt < 4; dt++) acc[m][dt][r] *= c;
          Pl[w][(m * 16 + lg * 4 + r) * 32 + lr]      = f2bf(p0);
          Pl[w][(m * 16 + lg * 4 + r) * 32 + 16 + lr] = f2bf(p1);
        }
      }
    }
    __syncthreads();   // P visible (and scores done) before PV reads
    if (active) {
#pragma unroll
      for (int m = 0; m < 2; m++) {
        bf16x8 pf = *reinterpret_cast<const bf16x8*>(&Pl[w][(m * 16 + lr) * 32 + lg * 8]);
#pragma unroll
        for (int dt = 0; dt < 4; dt++) {
          bf16x8 vf = *reinterpret_cast<const bf16x8*>(&Vl[(dt * 16 + lr) * 32 + lg * 8]);
          acc[m][dt] = mfma16(pf, vf, acc[m][dt]);
        }
      }
    }
    __syncthreads();   // LDS free before next stage
  }

  // epilogue: normalize, write context [B*S, D] bf16
#pragma unroll
  for (int m = 0; m < 2; m++) {
#pragma unroll
    for (int dt = 0; dt < 4; dt++) {
#pragma unroll
      for (int r = 0; r < 4; r++) {
        const int row = q0 + w * 32 + m * 16 + lg * 4 + r;   // s
        const int col = h * DK_ + dt * 16 + lr;              // feature
        const float o = acc[m][dt][r] / lrun[m][r];
        Cb[((size_t)b * S_ + row) * D_ + col] = f2bf(o);
      }
    }
  }
}

// ---------------------------------------------------------------- output GEMM
__global__ __launch_bounds__(256)
void SAA_gemm_out(const unsigned short* __restrict__ Cb,
                  const unsigned short* __restrict__ Wob,
                  const float* __restrict__ bo,
                  float* __restrict__ Y)
{
  const int K = D_;
  __shared__ __attribute__((aligned(16))) unsigned short lA[128 * 32];
  __shared__ __attribute__((aligned(16))) unsigned short lB[128 * 32];

  const int t = threadIdx.x;
  const int w = t >> 6, l = t & 63;
  const int wr = w >> 1, wc = w & 1;
  const int lr = l & 15, lg = l >> 4;

  const int m0 = blockIdx.y * 128;
  const int n0 = blockIdx.x * 128;

  const unsigned short* gA = Cb + (size_t)m0 * K;
  const unsigned short* gB = Wob + (size_t)n0 * K;

  const int srow = t >> 2, skoff = (t & 3) * 8;

  f32x4 acc[4][4] = {};

  for (int k0 = 0; k0 < K; k0 += 32) {
    gl_lds16(gA + (size_t)srow * K + k0 + skoff,        &lA[t * 8]);
    gl_lds16(gA + (size_t)(srow + 64) * K + k0 + skoff, &lA[2048 + t * 8]);
    gl_lds16(gB + (size_t)srow * K + k0 + skoff,        &lB[t * 8]);
    gl_lds16(gB + (size_t)(srow + 64) * K + k0 + skoff, &lB[2048 + t * 8]);
    __syncthreads();

    bf16x8 af[4], bfr[4];
#pragma unroll
    for (int i = 0; i < 4; i++)
      af[i] = *reinterpret_cast<const bf16x8*>(&lA[(wr * 64 + i * 16 + lr) * 32 + lg * 8]);
#pragma unroll
    for (int j = 0; j < 4; j++)
      bfr[j] = *reinterpret_cast<const bf16x8*>(&lB[(wc * 64 + j * 16 + lr) * 32 + lg * 8]);
#pragma unroll
    for (int i = 0; i < 4; i++)
#pragma unroll
      for (int j = 0; j < 4; j++)
        acc[i][j] = mfma16(af[i], bfr[j], acc[i][j]);
    __syncthreads();
  }

#pragma unroll
  for (int j = 0; j < 4; j++) {
    const int col = n0 + wc * 64 + j * 16 + lr;
    const float bsv = bo[col];
#pragma unroll
    for (int i = 0; i < 4; i++) {
#pragma unroll
      for (int r = 0; r < 4; r++) {
        const int row = m0 + wr * 64 + i * 16 + lg * 4 + r;
        Y[(size_t)row * D_ + col] = acc[i][j][r] + bsv;
      }
    }
  }
}

// ---------------------------------------------------------------- launch
extern "C" void kernel_launch(void* const* d_in, const int* in_sizes, int n_in,
                              void* d_out, int out_size, void* d_ws, size_t ws_size,
                              hipStream_t stream) {
  const float* input = (const float*)d_in[0];
  const float* rw    = (const float*)d_in[1];
  const int*   maskp = (const int*)d_in[2];
  const float* Wq = (const float*)d_in[3];
  const float* bq = (const float*)d_in[4];
  const float* Wk = (const float*)d_in[5];
  const float* bk = (const float*)d_in[6];
  const float* Wv = (const float*)d_in[7];
  const float* bv = (const float*)d_in[8];
  const float* Wo = (const float*)d_in[9];
  const float* bo = (const float*)d_in[10];

  char* ws = (char*)d_ws;
  unsigned short* Xb  = (unsigned short*)(ws);                 // 16 MB (reused as Cb)
  unsigned short* Wqb = (unsigned short*)(ws + (16u << 20));   // 2 MB each
  unsigned short* Wkb = (unsigned short*)(ws + (18u << 20));
  unsigned short* Wvb = (unsigned short*)(ws + (20u << 20));
  unsigned short* Wob = (unsigned short*)(ws + (22u << 20));
  unsigned short* Qo  = (unsigned short*)(ws + (24u << 20));   // 16 MB
  unsigned short* Ko  = (unsigned short*)(ws + (40u << 20));   // 16 MB
  unsigned short* Vto = (unsigned short*)(ws + (56u << 20));   // 16 MB
  unsigned short* Cb  = Xb;   // Xb dead after QKV GEMM

  SAA_cast_bf16<<<2048, 256, 0, stream>>>(input, Xb, (B_ * S_ * D_) / 4);
  SAA_cast_bf16<<<1024, 256, 0, stream>>>(Wq, Wqb, (D_ * D_) / 4);
  SAA_cast_bf16<<<1024, 256, 0, stream>>>(Wk, Wkb, (D_ * D_) / 4);
  SAA_cast_bf16<<<1024, 256, 0, stream>>>(Wv, Wvb, (D_ * D_) / 4);
  SAA_cast_bf16<<<1024, 256, 0, stream>>>(Wo, Wob, (D_ * D_) / 4);

  SAA_gemm_qkv<<<dim3(8, 64, 3), 256, 0, stream>>>(Xb, Wqb, Wkb, Wvb, bq, bk, bv,
                                                   Qo, Ko, Vto);
  SAA_attn<<<dim3(16, 16, 4), 256, 0, stream>>>(Qo, Ko, Vto, rw, maskp, Cb);
  SAA_gemm_out<<<dim3(8, 64, 1), 256, 0, stream>>>(Cb, Wob, bo, (float*)d_out);
}

// Round 2
// 275.931 us; speedup vs baseline: 1.7268x; 1.7268x over previous
//
#include <hip/hip_runtime.h>
#include <math.h>

// Problem constants
#define B_  4
#define S_  2048
#define D_  1024
#define H_  16
#define DK_ 64
#define M_  (B_*S_)   // 8192

typedef __bf16 bf16x8 __attribute__((ext_vector_type(8)));
typedef float  f32x4  __attribute__((ext_vector_type(4)));

__device__ __forceinline__ unsigned short f2bf(float f) {
  unsigned int u = __builtin_bit_cast(unsigned int, f);
  u += 0x7fffu + ((u >> 16) & 1u);   // round to nearest even
  return (unsigned short)(u >> 16);
}

__device__ __forceinline__ f32x4 mfma16(bf16x8 a, bf16x8 b, f32x4 c) {
  return __builtin_amdgcn_mfma_f32_16x16x32_bf16(a, b, c, 0, 0, 0);
}

__device__ __forceinline__ void gl_lds16(const unsigned short* g, unsigned short* l) {
  __builtin_amdgcn_global_load_lds(
      (const __attribute__((address_space(1))) void*)g,
      (__attribute__((address_space(3))) void*)l, 16, 0, 0);
}

// ---------------------------------------------------------------- cast f32->bf16
__global__ void SAA_cast_bf16(const float* __restrict__ src,
                              unsigned short* __restrict__ dst, int n4) {
  int i = blockIdx.x * blockDim.x + threadIdx.x;
  int stride = gridDim.x * blockDim.x;
  for (; i < n4; i += stride) {
    float4 v = reinterpret_cast<const float4*>(src)[i];
    ushort4 o;
    o.x = f2bf(v.x); o.y = f2bf(v.y); o.z = f2bf(v.z); o.w = f2bf(v.w);
    reinterpret_cast<ushort4*>(dst)[i] = o;
  }
}

// ---------------------------------------------------------------- QKV GEMM
// C[m,n] = sum_k Xb[m,k] * W[n,k] + bias[n]   (torch Linear: x @ W.T + b)
// 128x128 tile, BK=32, 4 waves (2x2), each wave 64x64 (4x4 frags of 16x16).
__global__ __launch_bounds__(256)
void SAA_gemm_qkv(const unsigned short* __restrict__ Xb,
                  const unsigned short* __restrict__ Wqb,
                  const unsigned short* __restrict__ Wkb,
                  const unsigned short* __restrict__ Wvb,
                  const float* __restrict__ bq,
                  const float* __restrict__ bk,
                  const float* __restrict__ bv,
                  unsigned short* __restrict__ Qo,
                  unsigned short* __restrict__ Ko,
                  unsigned short* __restrict__ Vto)
{
  const int K = D_;
  const int wid = blockIdx.z;
  const unsigned short* W = (wid == 0) ? Wqb : ((wid == 1) ? Wkb : Wvb);
  const float* bias = (wid == 0) ? bq : ((wid == 1) ? bk : bv);

  __shared__ __attribute__((aligned(16))) unsigned short lA[128 * 32];
  __shared__ __attribute__((aligned(16))) unsigned short lB[128 * 32];

  const int t = threadIdx.x;
  const int w = t >> 6, l = t & 63;
  const int wr = w >> 1, wc = w & 1;
  const int lr = l & 15, lg = l >> 4;

  const int m0 = blockIdx.y * 128;
  const int n0 = blockIdx.x * 128;

  const unsigned short* gA = Xb + (size_t)m0 * K;
  const unsigned short* gB = W + (size_t)n0 * K;

  const int srow = t >> 2, skoff = (t & 3) * 8;

  f32x4 acc[4][4] = {};

  for (int k0 = 0; k0 < K; k0 += 32) {
    gl_lds16(gA + (size_t)srow * K + k0 + skoff,        &lA[t * 8]);
    gl_lds16(gA + (size_t)(srow + 64) * K + k0 + skoff, &lA[2048 + t * 8]);
    gl_lds16(gB + (size_t)srow * K + k0 + skoff,        &lB[t * 8]);
    gl_lds16(gB + (size_t)(srow + 64) * K + k0 + skoff, &lB[2048 + t * 8]);
    __syncthreads();

    bf16x8 af[4], bfr[4];
#pragma unroll
    for (int i = 0; i < 4; i++)
      af[i] = *reinterpret_cast<const bf16x8*>(&lA[(wr * 64 + i * 16 + lr) * 32 + lg * 8]);
#pragma unroll
    for (int j = 0; j < 4; j++)
      bfr[j] = *reinterpret_cast<const bf16x8*>(&lB[(wc * 64 + j * 16 + lr) * 32 + lg * 8]);
#pragma unroll
    for (int i = 0; i < 4; i++)
#pragma unroll
      for (int j = 0; j < 4; j++)
        acc[i][j] = mfma16(af[i], bfr[j], acc[i][j]);
    __syncthreads();
  }

  // epilogue: bias add, cast, scatter into attention layouts
#pragma unroll
  for (int j = 0; j < 4; j++) {
    const int col = n0 + wc * 64 + j * 16 + lr;   // 0..1023 = feature d
    const float bsv = bias[col];
    const int h = col >> 6, dk = col & 63;
#pragma unroll
    for (int i = 0; i < 4; i++) {
#pragma unroll
      for (int r = 0; r < 4; r++) {
        const int row = m0 + wr * 64 + i * 16 + lg * 4 + r;  // 0..8191 = token
        const int b = row >> 11, s = row & 2047;
        const unsigned short val = f2bf(acc[i][j][r] + bsv);
        if (wid == 2)
          Vto[(((size_t)b * H_ + h) * DK_ + dk) * S_ + s] = val;       // [B,H,DK,S]
        else if (wid == 0)
          Qo[(((size_t)b * H_ + h) * S_ + s) * DK_ + dk] = val;        // [B,H,S,DK]
        else
          Ko[(((size_t)b * H_ + h) * S_ + s) * DK_ + dk] = val;
      }
    }
  }
}

// ---------------------------------------------------------------- flash attention
// block = (q-block PAIR {p, 15-p}, h, b); 4 waves x 32 queries each; KV tiles of 64.
// K/V/P LDS tiles have 128B rows -> XOR-swizzle 16B chunks by (row&7) to kill
// the 16-way bank conflicts (global source pre-swizzled; gl_lds dest stays linear).
__global__ __launch_bounds__(256)
void SAA_attn(const unsigned short* __restrict__ Q,
              const unsigned short* __restrict__ Kb,
              const unsigned short* __restrict__ Vt,
              const float* __restrict__ rw,
              const int* __restrict__ maskp,
              unsigned short* __restrict__ Cb)
{
  const int pairid = blockIdx.x;                 // 0..7
  const int h = blockIdx.y, b = blockIdx.z;
  const int t = threadIdx.x, w = t >> 6, l = t & 63;
  const int lr = l & 15, lg = l >> 4;
  const int mask = maskp[0];

  __shared__ __attribute__((aligned(16))) unsigned short Kt[2][64 * 64];  // [key][dk] swz
  __shared__ __attribute__((aligned(16))) unsigned short Vl[2][64 * 64];  // [dk][key] swz
  __shared__ __attribute__((aligned(16))) unsigned short Pl[4][32 * 64];  // [q][key]  swz

  const size_t bh = (size_t)b * H_ + h;
  const unsigned short* Qbh = Q + bh * S_ * DK_;
  const unsigned short* Kbh = Kb + bh * S_ * DK_;
  const unsigned short* Vbh = Vt + bh * DK_ * S_;
  const float* rwb = rw + b * S_;
  unsigned short* Pw = &Pl[w][0];

  // staging geometry: 512 chunks of 16B per tile, thread t owns chunks t and t+256
  const int r0 = t >> 3, cc0 = t & 7;            // chunk t   -> row r0,    col-chunk cc0
  const int r1 = 32 + (t >> 3);                  // chunk t+256
  const int sw0 = (cc0 ^ (r0 & 7)) * 8;          // pre-swizzled source offset (shorts)
  const int sw1 = (cc0 ^ (r1 & 7)) * 8;          // (r1&7)==(r0&7) but keep explicit

  for (int half = 0; half < 2; ++half) {
    const int qb = half ? (15 - pairid) : pairid;
    const int q0 = qb * 128;

    // Q fragments: rows q0+w*32+m*16+lr, k = ks*32 + lg*8
    bf16x8 qf[2][2];
#pragma unroll
    for (int m = 0; m < 2; m++)
#pragma unroll
      for (int ks = 0; ks < 2; ks++)
        qf[m][ks] = *reinterpret_cast<const bf16x8*>(
            &Qbh[(size_t)(q0 + w * 32 + m * 16 + lr) * DK_ + ks * 32 + lg * 8]);

    f32x4 acc[2][4] = {};
    float mrun[2][4], lrun[2][4];
#pragma unroll
    for (int m = 0; m < 2; m++)
#pragma unroll
      for (int r = 0; r < 4; r++) { mrun[m][r] = -INFINITY; lrun[m][r] = 0.f; }

    const int nkt = mask ? (qb * 2 + 2) : (S_ / 64);   // always even
    const int wqmax = q0 + w * 32 + 31;

    __syncthreads();   // previous half's readers done before we restage buf 0

    // prologue: stage tile 0 into buf 0
    {
      const int k0 = 0;
      gl_lds16(Kbh + (size_t)(k0 + r0) * DK_ + sw0, &Kt[0][t * 8]);
      gl_lds16(Kbh + (size_t)(k0 + r1) * DK_ + sw1, &Kt[0][2048 + t * 8]);
      gl_lds16(Vbh + (size_t)r0 * S_ + k0 + sw0,    &Vl[0][t * 8]);
      gl_lds16(Vbh + (size_t)r1 * S_ + k0 + sw1,    &Vl[0][2048 + t * 8]);
    }
    int cur = 0;

    for (int kt = 0; kt < nkt; ++kt) {
      __syncthreads();      // drains staged loads for buf[cur]; frees buf[cur^1]
      if (kt + 1 < nkt) {   // prefetch next tile into the other buffer
        const int kn = (kt + 1) * 64;
        const int nb = cur ^ 1;
        gl_lds16(Kbh + (size_t)(kn + r0) * DK_ + sw0, &Kt[nb][t * 8]);
        gl_lds16(Kbh + (size_t)(kn + r1) * DK_ + sw1, &Kt[nb][2048 + t * 8]);
        gl_lds16(Vbh + (size_t)r0 * S_ + kn + sw0,    &Vl[nb][t * 8]);
        gl_lds16(Vbh + (size_t)r1 * S_ + kn + sw1,    &Vl[nb][2048 + t * 8]);
      }

      const int k0 = kt * 64;
      const bool active = (!mask) || (k0 <= wqmax);
      if (active) {
        const unsigned short* Kc = &Kt[cur][0];
        const unsigned short* Vc = &Vl[cur][0];

        // QK^T: sc[m][t2] over 4 key sub-tiles
        f32x4 sc[2][4] = {};
#pragma unroll
        for (int ks = 0; ks < 2; ++ks) {
          const int swk = (((ks * 4 + lg) ^ (lr & 7)) << 3);
#pragma unroll
          for (int t2 = 0; t2 < 4; ++t2) {
            bf16x8 kf = *reinterpret_cast<const bf16x8*>(&Kc[(t2 * 16 + lr) * 64 + swk]);
            sc[0][t2] = mfma16(qf[0][ks], kf, sc[0][t2]);
            sc[1][t2] = mfma16(qf[1][ks], kf, sc[1][t2]);
          }
        }

        float rwv[4]; int key[4];
#pragma unroll
        for (int t2 = 0; t2 < 4; ++t2) {
          key[t2] = k0 + t2 * 16 + lr;
          rwv[t2] = rwb[key[t2]] * 0.125f;
        }

#pragma unroll
        for (int m = 0; m < 2; m++) {
#pragma unroll
          for (int r = 0; r < 4; r++) {
            const int row = q0 + w * 32 + m * 16 + lg * 4 + r;
            float v[4];
#pragma unroll
            for (int t2 = 0; t2 < 4; ++t2) {
              v[t2] = sc[m][t2][r];
              if (mask && key[t2] > row) v[t2] -= 1e9f;
              v[t2] *= rwv[t2];
            }
            float mx = fmaxf(fmaxf(v[0], v[1]), fmaxf(v[2], v[3]));
            mx = fmaxf(mx, __shfl_xor(mx, 1));
            mx = fmaxf(mx, __shfl_xor(mx, 2));
            mx = fmaxf(mx, __shfl_xor(mx, 4));
            mx = fmaxf(mx, __shfl_xor(mx, 8));
            const float mnew = fmaxf(mrun[m][r], mx);
            const float c = __expf(mrun[m][r] - mnew);
            mrun[m][r] = mnew;
            float p0 = __expf(v[0] - mnew);
            float p1 = __expf(v[1] - mnew);
            float p2 = __expf(v[2] - mnew);
            float p3 = __expf(v[3] - mnew);
            float rs = (p0 + p1) + (p2 + p3);
            rs += __shfl_xor(rs, 1);
            rs += __shfl_xor(rs, 2);
            rs += __shfl_xor(rs, 4);
            rs += __shfl_xor(rs, 8);
            lrun[m][r] = lrun[m][r] * c + rs;
#pragma unroll
            for (int dt = 0; dt < 4; dt++) acc[m][dt][r] *= c;
            const int prow = m * 16 + lg * 4 + r;
            const int pbase = prow * 64 + (lr & 7);
            Pw[pbase + (((0 + (lr >> 3)) ^ (prow & 7)) << 3)] = f2bf(p0);
            Pw[pbase + (((2 + (lr >> 3)) ^ (prow & 7)) << 3)] = f2bf(p1);
            Pw[pbase + (((4 + (lr >> 3)) ^ (prow & 7)) << 3)] = f2bf(p2);
            Pw[pbase + (((6 + (lr >> 3)) ^ (prow & 7)) << 3)] = f2bf(p3);
          }
        }

        // PV: acc[m][dt] += P[m-rows][keys] * V[keys][dt-cols]
#pragma unroll
        for (int ks = 0; ks < 2; ++ks) {
          const int swk = (((ks * 4 + lg) ^ (lr & 7)) << 3);
          bf16x8 pf0 = *reinterpret_cast<const bf16x8*>(&Pw[(0 * 16 + lr) * 64 + swk]);
          bf16x8 pf1 = *reinterpret_cast<const bf16x8*>(&Pw[(1 * 16 + lr) * 64 + swk]);
#pragma unroll
          for (int dt = 0; dt < 4; ++dt) {
            bf16x8 vf = *reinterpret_cast<const bf16x8*>(&Vc[(dt * 16 + lr) * 64 + swk]);
            acc[0][dt] = mfma16(pf0, vf, acc[0][dt]);
            acc[1][dt] = mfma16(pf1, vf, acc[1][dt]);
          }
        }
      }
      cur ^= 1;
    }

    // epilogue: normalize, write context [B*S, D] bf16
#pragma unroll
    for (int m = 0; m < 2; m++) {
#pragma unroll
      for (int dt = 0; dt < 4; dt++) {
#pragma unroll
        for (int r = 0; r < 4; r++) {
          const int row = q0 + w * 32 + m * 16 + lg * 4 + r;   // s
          const int col = h * DK_ + dt * 16 + lr;              // feature
          const float o = acc[m][dt][r] / lrun[m][r];
          Cb[((size_t)b * S_ + row) * D_ + col] = f2bf(o);
        }
      }
    }
  }
}

// ---------------------------------------------------------------- output GEMM
__global__ __launch_bounds__(256)
void SAA_gemm_out(const unsigned short* __restrict__ Cb,
                  const unsigned short* __restrict__ Wob,
                  const float* __restrict__ bo,
                  float* __restrict__ Y)
{
  const int K = D_;
  __shared__ __attribute__((aligned(16))) unsigned short lA[128 * 32];
  __shared__ __attribute__((aligned(16))) unsigned short lB[128 * 32];

  const int t = threadIdx.x;
  const int w = t >> 6, l = t & 63;
  const int wr = w >> 1, wc = w & 1;
  const int lr = l & 15, lg = l >> 4;

  const int m0 = blockIdx.y * 128;
  const int n0 = blockIdx.x * 128;

  const unsigned short* gA = Cb + (size_t)m0 * K;
  const unsigned short* gB = Wob + (size_t)n0 * K;

  const int srow = t >> 2, skoff = (t & 3) * 8;

  f32x4 acc[4][4] = {};

  for (int k0 = 0; k0 < K; k0 += 32) {
    gl_lds16(gA + (size_t)srow * K + k0 + skoff,        &lA[t * 8]);
    gl_lds16(gA + (size_t)(srow + 64) * K + k0 + skoff, &lA[2048 + t * 8]);
    gl_lds16(gB + (size_t)srow * K + k0 + skoff,        &lB[t * 8]);
    gl_lds16(gB + (size_t)(srow + 64) * K + k0 + skoff, &lB[2048 + t * 8]);
    __syncthreads();

    bf16x8 af[4], bfr[4];
#pragma unroll
    for (int i = 0; i < 4; i++)
      af[i] = *reinterpret_cast<const bf16x8*>(&lA[(wr * 64 + i * 16 + lr) * 32 + lg * 8]);
#pragma unroll
    for (int j = 0; j < 4; j++)
      bfr[j] = *reinterpret_cast<const bf16x8*>(&lB[(wc * 64 + j * 16 + lr) * 32 + lg * 8]);
#pragma unroll
    for (int i = 0; i < 4; i++)
#pragma unroll
      for (int j = 0; j < 4; j++)
        acc[i][j] = mfma16(af[i], bfr[j], acc[i][j]);
    __syncthreads();
  }

#pragma unroll
  for (int j = 0; j < 4; j++) {
    const int col = n0 + wc * 64 + j * 16 + lr;
    const float bsv = bo[col];
#pragma unroll
    for (int i = 0; i < 4; i++) {
#pragma unroll
      for (int r = 0; r < 4; r++) {
        const int row = m0 + wr * 64 + i * 16 + lg * 4 + r;
        Y[(size_t)row * D_ + col] = acc[i][j][r] + bsv;
      }
    }
  }
}

// ---------------------------------------------------------------- launch
extern "C" void kernel_launch(void* const* d_in, const int* in_sizes, int n_in,
                              void* d_out, int out_size, void* d_ws, size_t ws_size,
                              hipStream_t stream) {
  const float* input = (const float*)d_in[0];
  const float* rw    = (const float*)d_in[1];
  const int*   maskp = (const int*)d_in[2];
  const float* Wq = (const float*)d_in[3];
  const float* bq = (const float*)d_in[4];
  const float* Wk = (const float*)d_in[5];
  const float* bk = (const float*)d_in[6];
  const float* Wv = (const float*)d_in[7];
  const float* bv = (const float*)d_in[8];
  const float* Wo = (const float*)d_in[9];
  const float* bo = (const float*)d_in[10];

  char* ws = (char*)d_ws;
  unsigned short* Xb  = (unsigned short*)(ws);                 // 16 MB (reused as Cb)
  unsigned short* Wqb = (unsigned short*)(ws + (16u << 20));   // 2 MB each
  unsigned short* Wkb = (unsigned short*)(ws + (18u << 20));
  unsigned short* Wvb = (unsigned short*)(ws + (20u << 20));
  unsigned short* Wob = (unsigned short*)(ws + (22u << 20));
  unsigned short* Qo  = (unsigned short*)(ws + (24u << 20));   // 16 MB
  unsigned short* Ko  = (unsigned short*)(ws + (40u << 20));   // 16 MB
  unsigned short* Vto = (unsigned short*)(ws + (56u << 20));   // 16 MB
  unsigned short* Cb  = Xb;   // Xb dead after QKV GEMM

  SAA_cast_bf16<<<2048, 256, 0, stream>>>(input, Xb, (B_ * S_ * D_) / 4);
  SAA_cast_bf16<<<1024, 256, 0, stream>>>(Wq, Wqb, (D_ * D_) / 4);
  SAA_cast_bf16<<<1024, 256, 0, stream>>>(Wk, Wkb, (D_ * D_) / 4);
  SAA_cast_bf16<<<1024, 256, 0, stream>>>(Wv, Wvb, (D_ * D_) / 4);
  SAA_cast_bf16<<<1024, 256, 0, stream>>>(Wo, Wob, (D_ * D_) / 4);

  SAA_gemm_qkv<<<dim3(8, 64, 3), 256, 0, stream>>>(Xb, Wqb, Wkb, Wvb, bq, bk, bv,
                                                   Qo, Ko, Vto);
  SAA_attn<<<dim3(8, 16, 4), 256, 0, stream>>>(Qo, Ko, Vto, rw, maskp, Cb);
  SAA_gemm_out<<<dim3(8, 64, 1), 256, 0, stream>>>(Cb, Wob, bo, (float*)d_out);
}